// Round 13
// baseline (131.704 us; speedup 1.0000x reference)
//
#include <hip/hip_runtime.h>
#include <stdint.h>

// Problem constants (match reference)
#define B_ 4096
#define C_ 200
#define P_ 32
#define F_ 512
#define N_ (C_*P_)        // 6400 prototypes total
#define ALPHA_ 5.0
#define EPS_ 1e-8

typedef unsigned char u8;
typedef unsigned int u32;
typedef __attribute__((ext_vector_type(4))) float floatx4;  // MFMA C/D frag

union frag16 { int4 v; long l[2]; };   // 16 fp8 = two MFMA k-slices (virtual-K)

// ---------- prep: fp32 -> fp8 e4m3 packed + row sum-of-squares, NO atomics ----------
// Packed layout: o = tm*512 + kc*64 + q*16 + r (16-B units); byte (tm*8+kc)*1024 +
// (q*16+r)*16 holds features [kc*64+q*16,+16) of row tm*16+r.
// One 256-thread block covers one FULL row-tile tm (each thread converts units o and
// o+256, i.e. kc and kc+4): the 16 per-row partials live in one block -> LDS reduce ->
// direct sumsq store. zero_kernel and global atomics eliminated.
// Blocks [0,256) = A (outputs -> x2), [256,656) = B (clusters -> p2).
__global__ __launch_bounds__(256)
void prep_kernel(const float* __restrict__ outputs, const float* __restrict__ clusters,
                 u8* __restrict__ At, u8* __restrict__ Bt, float* __restrict__ sumsq,
                 u32* __restrict__ counter) {
    __shared__ float part[256];
    const int tid = threadIdx.x;
    const int blk = blockIdx.x;
    const float* src; u8* dst; int tm, rbase;
    if (blk < 256) { tm = blk;       src = outputs;  dst = At; rbase = 0; }
    else           { tm = blk - 256; src = clusters; dst = Bt; rbase = B_; }
    const int kc = tid >> 6, q = (tid >> 4) & 3, r = tid & 15;
    const int row = tm * 16 + r;
    const float* base = src + (size_t)row * F_;

    const float4* s0 = (const float4*)(base + kc * 64 + q * 16);
    const float4* s1 = (const float4*)(base + (kc + 4) * 64 + q * 16);
    float4 v0 = s0[0], v1 = s0[1], v2 = s0[2], v3 = s0[3];
    float4 u0 = s1[0], u1 = s1[1], u2 = s1[2], u3 = s1[3];
    int4 w;
    w.x = __builtin_amdgcn_cvt_pk_fp8_f32(v0.x, v0.y, 0, false);
    w.x = __builtin_amdgcn_cvt_pk_fp8_f32(v0.z, v0.w, w.x, true);
    w.y = __builtin_amdgcn_cvt_pk_fp8_f32(v1.x, v1.y, 0, false);
    w.y = __builtin_amdgcn_cvt_pk_fp8_f32(v1.z, v1.w, w.y, true);
    w.z = __builtin_amdgcn_cvt_pk_fp8_f32(v2.x, v2.y, 0, false);
    w.z = __builtin_amdgcn_cvt_pk_fp8_f32(v2.z, v2.w, w.z, true);
    w.w = __builtin_amdgcn_cvt_pk_fp8_f32(v3.x, v3.y, 0, false);
    w.w = __builtin_amdgcn_cvt_pk_fp8_f32(v3.z, v3.w, w.w, true);
    const size_t o = (size_t)tm * 512 + tid;
    *(int4*)(dst + o * 16) = w;
    w.x = __builtin_amdgcn_cvt_pk_fp8_f32(u0.x, u0.y, 0, false);
    w.x = __builtin_amdgcn_cvt_pk_fp8_f32(u0.z, u0.w, w.x, true);
    w.y = __builtin_amdgcn_cvt_pk_fp8_f32(u1.x, u1.y, 0, false);
    w.y = __builtin_amdgcn_cvt_pk_fp8_f32(u1.z, u1.w, w.y, true);
    w.z = __builtin_amdgcn_cvt_pk_fp8_f32(u2.x, u2.y, 0, false);
    w.z = __builtin_amdgcn_cvt_pk_fp8_f32(u2.z, u2.w, w.z, true);
    w.w = __builtin_amdgcn_cvt_pk_fp8_f32(u3.x, u3.y, 0, false);
    w.w = __builtin_amdgcn_cvt_pk_fp8_f32(u3.z, u3.w, w.w, true);
    *(int4*)(dst + (o + 256) * 16) = w;

    part[tid] = v0.x*v0.x + v0.y*v0.y + v0.z*v0.z + v0.w*v0.w
              + v1.x*v1.x + v1.y*v1.y + v1.z*v1.z + v1.w*v1.w
              + v2.x*v2.x + v2.y*v2.y + v2.z*v2.z + v2.w*v2.w
              + v3.x*v3.x + v3.y*v3.y + v3.z*v3.z + v3.w*v3.w
              + u0.x*u0.x + u0.y*u0.y + u0.z*u0.z + u0.w*u0.w
              + u1.x*u1.x + u1.y*u1.y + u1.z*u1.z + u1.w*u1.w
              + u2.x*u2.x + u2.y*u2.y + u2.z*u2.z + u2.w*u2.w
              + u3.x*u3.x + u3.y*u3.y + u3.z*u3.z + u3.w*u3.w;
    __syncthreads();
    if (tid < 16) {
        float acc = 0.f;
#pragma unroll
        for (int j = 0; j < 16; ++j) acc += part[tid + j * 16];
        sumsq[rbase + tm * 16 + tid] = acc;
    }
    if (blk == 0 && tid == 0) *counter = 0;   // reset select's done-counter (stream-ordered)
}

// ---------- score kernel: fp8 MFMA GEMM (R8's proven 44us version, unchanged) ----------
#define BM 128
#define BN 128

typedef const __attribute__((address_space(1))) unsigned int gu32_t;
typedef __attribute__((address_space(3))) unsigned int lu32_t;

__device__ __forceinline__ void gld16(const u8* g, u8* l) {
    __builtin_amdgcn_global_load_lds((gu32_t*)g, (lu32_t*)l, 16, 0, 0);
}

__global__ __launch_bounds__(256, 4)
void score_kernel(const u8* __restrict__ At, const u8* __restrict__ Bt,
                  const float* __restrict__ p2, float* __restrict__ min_d) {
    __shared__ __align__(16) u8 lds[2][16384];   // [buf][ A: 8 tiles x 1KB | B: 8 tiles x 1KB ]

    const int tid  = threadIdx.x;
    const int lane = tid & 63;
    const int w    = tid >> 6;          // wave 0..3 (2x2 wave grid, 64x64 per wave)
    const int wm   = w >> 1, wn = w & 1;
    const int bx   = blockIdx.x;        // n-tile 0..49
    const int by   = blockIdx.y;        // m-tile 0..31
    const int m0   = by * BM, n0 = bx * BN;
    const int mrow = lane & 15;
    const int quad = lane >> 4;
    const int l16  = lane * 16;

    const u8* ag = At + ((size_t)(by * 8) << 13);   // 8 row-tiles x 8KB each
    const u8* bg = Bt + ((size_t)(bx * 8) << 13);

    floatx4 zf = {0.f, 0.f, 0.f, 0.f};
    floatx4 acc[4][4];
#pragma unroll
    for (int i = 0; i < 4; ++i)
#pragma unroll
        for (int j = 0; j < 4; ++j) acc[i][j] = zf;

    // prologue: prefetch stage 0 into buf 0 (wave w loads A tiles {w,w+4}, B tiles {w,w+4})
    gld16(ag + ((w * 8) << 10) + l16,           lds[0] + w * 1024);
    gld16(ag + (((w + 4) * 8) << 10) + l16,     lds[0] + (w + 4) * 1024);
    gld16(bg + ((w * 8) << 10) + l16,           lds[0] + 8192 + w * 1024);
    gld16(bg + (((w + 4) * 8) << 10) + l16,     lds[0] + 8192 + (w + 4) * 1024);
    __syncthreads();

#pragma unroll
    for (int kc = 0; kc < 8; ++kc) {
        const int cur = kc & 1;
        if (kc < 7) {
            const int nb = cur ^ 1, kn = kc + 1;
            gld16(ag + ((w * 8 + kn) << 10) + l16,         lds[nb] + w * 1024);
            gld16(ag + (((w + 4) * 8 + kn) << 10) + l16,   lds[nb] + (w + 4) * 1024);
            gld16(bg + ((w * 8 + kn) << 10) + l16,         lds[nb] + 8192 + w * 1024);
            gld16(bg + (((w + 4) * 8 + kn) << 10) + l16,   lds[nb] + 8192 + (w + 4) * 1024);
        }
        frag16 a[4], b[4];
#pragma unroll
        for (int t = 0; t < 4; ++t) {
            a[t].v = *(const int4*)(lds[cur] + (wm * 4 + t) * 1024 + l16);
            b[t].v = *(const int4*)(lds[cur] + 8192 + (wn * 4 + t) * 1024 + l16);
        }
#pragma unroll
        for (int s = 0; s < 2; ++s)
#pragma unroll
            for (int mt = 0; mt < 4; ++mt)
#pragma unroll
                for (int nt = 0; nt < 4; ++nt)
                    acc[mt][nt] = __builtin_amdgcn_mfma_f32_16x16x32_fp8_fp8(
                        a[mt].l[s], b[nt].l[s], acc[mt][nt], 0, 0, 0);
        __syncthreads();
    }

    // Epilogue: score = p2[n] - 2*xp (x2 constant per row b — argmins unchanged).
    // C/D layout: col = lane&15, row = quad*4 + reg.
    float pg[4];
#pragma unroll
    for (int nt = 0; nt < 4; ++nt) pg[nt] = p2[n0 + wn * 64 + nt * 16 + mrow];

#pragma unroll
    for (int ch = 0; ch < 2; ++ch) {
        const int cls = bx * 4 + wn * 2 + ch;
#pragma unroll
        for (int mt = 0; mt < 4; ++mt)
#pragma unroll
            for (int reg = 0; reg < 4; ++reg) {
                float v = fminf(pg[ch * 2]     - 2.0f * acc[mt][ch * 2][reg],
                                pg[ch * 2 + 1] - 2.0f * acc[mt][ch * 2 + 1][reg]);
#pragma unroll
                for (int m = 8; m >= 1; m >>= 1) v = fminf(v, __shfl_xor(v, m));
                if (mrow == 0) {
                    int grow = m0 + wm * 64 + mt * 16 + quad * 4 + reg;
                    min_d[grow * C_ + cls] = v;
                }
            }
    }
}

// ---------- fused select + finalize (last-block-done; 1024 blocks keep occupancy) ----------
__global__ __launch_bounds__(256)
void select_kernel(const float* __restrict__ min_d, const float* __restrict__ x2,
                   const int* __restrict__ tgt,
                   float* __restrict__ stw, float* __restrict__ sww,
                   u32* __restrict__ counter, float* __restrict__ out) {
    __shared__ int last;
    __shared__ float r1[4], r2[4];
    const int tid = threadIdx.x, w = tid >> 6, lane = tid & 63;
    const int b  = blockIdx.x * 4 + w;
    const int tc = tgt[b];
    const float* row = min_d + (size_t)b * C_;

    float vt = row[tc];          // broadcast load
    float bw = 3.4e38f;
    for (int c = lane; c < C_; c += 64) {
        float v = row[c];
        if (c != tc) bw = fminf(bw, v);
    }
#pragma unroll
    for (int m = 32; m >= 1; m >>= 1) bw = fminf(bw, __shfl_xor(bw, m));
    if (lane == 0) {
        float xx = x2[b];
        stw[b] = xx + vt;        // = ||x - p_target*||^2 (fp8-dot approx)
        sww[b] = xx + bw;        // = ||x - p_wrong*||^2
    }
    __syncthreads();
    if (tid == 0) {
        __threadfence();
        last = (atomicAdd(counter, 1u) == (u32)(B_ / 4 - 1));
    }
    __syncthreads();
    if (!last) return;
    __threadfence();
    float s1 = 0.f, s2 = 0.f;
#pragma unroll
    for (int j = 0; j < 16; ++j) {
        int i = tid + j * 256;
        s1 += ((volatile const float*)stw)[i];
        s2 += ((volatile const float*)sww)[i];
    }
#pragma unroll
    for (int m = 32; m >= 1; m >>= 1) { s1 += __shfl_xor(s1, m); s2 += __shfl_xor(s2, m); }
    if (lane == 0) { r1[w] = s1; r2[w] = s2; }
    __syncthreads();
    if (tid == 0) {
        double t1 = (double)r1[0] + r1[1] + r1[2] + r1[3];
        double t2 = (double)r2[0] + r2[1] + r2[2] + r2[3];
        double denom = (double)B_ * (double)F_;
        double tl  = t1 / denom;
        double ntl = t2 / denom;
        out[0] = (float)((1.0 - ALPHA_) * tl + ALPHA_ / (ntl + EPS_));
    }
}

// ---------- launch ----------
extern "C" void kernel_launch(void* const* d_in, const int* in_sizes, int n_in,
                              void* d_out, int out_size, void* d_ws, size_t ws_size,
                              hipStream_t stream) {
    const float* outputs  = (const float*)d_in[0];
    const float* clusters = (const float*)d_in[1];
    const int*   tgt      = (const int*)d_in[2];
    float* out = (float*)d_out;

    char* ws = (char*)d_ws;
    // workspace layout (16B-aligned), total 8,692,752 bytes
    u8*     At      = (u8*)(ws);                     // packed A: 2,097,152
    u8*     Bt      = (u8*)(ws + 2097152);           // packed B: 3,276,800
    float*  sumsq   = (float*)(ws + 5373952);        // 10496*4 = 41,984 (x2 | p2)
    float*  min_d   = (float*)(ws + 5415936);        // 4096*200*4 = 3,276,800
    u32*    counter = (u32*)(ws + 8692736);          // 4
    float*  x2      = sumsq;
    float*  p2      = sumsq + B_;
    // per-sample partials: reuse the At region (dead after score_kernel)
    float*  stw     = (float*)(ws);                  // 4096*4
    float*  sww     = (float*)(ws + 16384);          // 4096*4

    prep_kernel<<<656, 256, 0, stream>>>(outputs, clusters, At, Bt, sumsq, counter);
    score_kernel<<<dim3(N_ / BN, B_ / BM), 256, 0, stream>>>(At, Bt, p2, min_d);   // 50x32
    select_kernel<<<B_ / 4, 256, 0, stream>>>(min_d, x2, tgt, stw, sww, counter, out);
}